// Round 1
// baseline (1425.246 us; speedup 1.0000x reference)
//
#include <hip/hip_runtime.h>
#include <stdint.h>

namespace {

constexpr int   B_   = 64;
constexpr int   F0_  = 1876;
constexpr int   F1_  = 1024;
constexpr int   F2_  = 10;
constexpr int   NT_  = 151;   // timesteps 0..150
constexpr int   NB1_ = 51;    // layer-1 bins: ti in [0,1) -> ceil(ti/dt) in [0,50]
constexpr float DT_  = 0.02f;
constexpr int   I40_ = F0_ / 4;   // 469
constexpr int   I41_ = F1_ / 4;   // 256

// ---------------------------------------------------------------------------
// K1: blocked transpose ti[b][i] -> tiT[i4][b][4]  (i = 4*i4+u)
// so that layer-1 lanes (lane=b) load float4 fully coalesced.
// ---------------------------------------------------------------------------
__global__ __launch_bounds__(256) void k_transpose(const float* __restrict__ ti,
                                                   float* __restrict__ tiT) {
  int t = blockIdx.x * 256 + threadIdx.x;
  if (t >= B_ * I40_) return;
  int b  = t / I40_;
  int i4 = t - b * I40_;
  // read coalesced along i within a row of ti (16B aligned: 1876 % 4 == 0)
  float4 v = *reinterpret_cast<const float4*>(ti + (size_t)b * F0_ + i4 * 4);
  *reinterpret_cast<float4*>(tiT + (size_t)i4 * (B_ * 4) + b * 4) = v;
}

// ---------------------------------------------------------------------------
// K2: layer 1.  One wave (64 threads) per block, lane = batch b.
// Each block handles 2 output neurons j (wave-uniform W rows -> s_load).
// Scatter-accumulate per-bin sums SA-bin, SC-bin into LDS with ds_add_f32,
// then per-lane prefix scan over 151 timesteps to find first mem >= 1.
// ---------------------------------------------------------------------------
__global__ __launch_bounds__(64) void k_layer1(const float* __restrict__ tiT,
                                               const float* __restrict__ W1,
                                               uint8_t* __restrict__ idx1T) {
  __shared__ float A[2][B_][NB1_];   // sum of W per bin
  __shared__ float C[2][B_][NB1_];   // sum of W*ti per bin
  const int lane = threadIdx.x;
  const int j0   = blockIdx.x * 2;

  for (int s = lane; s < 2 * B_ * NB1_; s += 64) {
    (&A[0][0][0])[s] = 0.0f;
    (&C[0][0][0])[s] = 0.0f;
  }
  __syncthreads();

  const float* __restrict__ w0 = W1 + (size_t)j0 * F0_;
  const float* __restrict__ w1 = w0 + F0_;

  for (int i4 = 0; i4 < I40_; ++i4) {
    float4 tv = *reinterpret_cast<const float4*>(tiT + (size_t)i4 * 256 + lane * 4);
    float4 wa = *reinterpret_cast<const float4*>(w0 + i4 * 4);   // uniform -> scalar load
    float4 wb = *reinterpret_cast<const float4*>(w1 + i4 * 4);   // uniform -> scalar load
    const float* tp  = reinterpret_cast<const float*>(&tv);
    const float* wap = reinterpret_cast<const float*>(&wa);
    const float* wbp = reinterpret_cast<const float*>(&wb);
#pragma unroll
    for (int u = 0; u < 4; ++u) {
      float t = tp[u];
      int k = (int)ceilf(t * 50.0f);          // ceil(ti/dt), dt = 0.02
      k = k < 0 ? 0 : (k > NB1_ - 1 ? NB1_ - 1 : k);
      float wA = wap[u], wB = wbp[u];
      atomicAdd(&A[0][lane][k], wA);
      atomicAdd(&C[0][lane][k], wA * t);
      atomicAdd(&A[1][lane][k], wB);
      atomicAdd(&C[1][lane][k], wB * t);
    }
  }
  __syncthreads();

#pragma unroll
  for (int jj = 0; jj < 2; ++jj) {
    float SA = 0.0f, SC = 0.0f;
    int idx = NT_ - 1;          // forced spike at last timestep
    bool found = false;
    for (int t = 0; t < NT_; ++t) {
      if (t < NB1_) { SA += A[jj][lane][t]; SC += C[jj][lane][t]; }
      float mem = (float)t * DT_ * SA - SC;
      if (!found && mem >= 1.0f) { idx = t; found = true; }
    }
    int j = j0 + jj;
    // blocked-transposed u8 store for layer-2 coalescing: idx1T[j4][b][4]
    idx1T[(size_t)(j >> 2) * 256 + lane * 4 + (j & 3)] = (uint8_t)idx;
  }
}

// ---------------------------------------------------------------------------
// K3: layer 2.  lane = batch b, one block per output neuron j (10 blocks).
// Input spike times are exactly k*dt (k = stored u8 index), bins 0..150.
// ---------------------------------------------------------------------------
__global__ __launch_bounds__(64) void k_layer2(const uint8_t* __restrict__ idx1T,
                                               const float* __restrict__ W2,
                                               float* __restrict__ out) {
  __shared__ float A[B_][NT_];
  __shared__ float C[B_][NT_];
  const int lane = threadIdx.x;
  const int j    = blockIdx.x;

  for (int s = lane; s < B_ * NT_; s += 64) {
    (&A[0][0])[s] = 0.0f;
    (&C[0][0])[s] = 0.0f;
  }
  __syncthreads();

  const float* __restrict__ w = W2 + (size_t)j * F1_;

  for (int i4 = 0; i4 < I41_; ++i4) {
    uint32_t kv = *reinterpret_cast<const uint32_t*>(idx1T + (size_t)i4 * 256 + lane * 4);
    float4 wv = *reinterpret_cast<const float4*>(w + i4 * 4);   // uniform -> scalar load
    const float* wp = reinterpret_cast<const float*>(&wv);
#pragma unroll
    for (int u = 0; u < 4; ++u) {
      int k = (int)((kv >> (8 * u)) & 0xFFu);
      float tv = (float)k * DT_;     // h1 value, bitwise == reference idx*0.02f
      float ww = wp[u];
      atomicAdd(&A[lane][k], ww);
      atomicAdd(&C[lane][k], ww * tv);
    }
  }
  __syncthreads();

  float SA = 0.0f, SC = 0.0f;
  int idx = NT_ - 1;
  bool found = false;
  for (int t = 0; t < NT_; ++t) {
    SA += A[lane][t]; SC += C[lane][t];
    float mem = (float)t * DT_ * SA - SC;
    if (!found && mem >= 1.0f) { idx = t; found = true; }
  }
  out[(size_t)lane * F2_ + j] = (float)idx * DT_;
}

}  // namespace

// ---------------------------------------------------------------------------
extern "C" void kernel_launch(void* const* d_in, const int* in_sizes, int n_in,
                              void* d_out, int out_size, void* d_ws, size_t ws_size,
                              hipStream_t stream) {
  const float* ti = (const float*)d_in[0];   // [64][1876]
  const float* W1 = (const float*)d_in[1];   // [1024][1876]
  const float* W2 = (const float*)d_in[2];   // [10][1024]
  float* out = (float*)d_out;                // [64][10]

  // workspace layout
  float*   tiT   = (float*)d_ws;                              // 120064 floats = 480256 B
  uint8_t* idx1T = (uint8_t*)d_ws + 480256;                   // 65536 B

  int n1 = B_ * I40_;  // 30016 threads
  hipLaunchKernelGGL(k_transpose, dim3((n1 + 255) / 256), dim3(256), 0, stream,
                     ti, tiT);
  hipLaunchKernelGGL(k_layer1, dim3(F1_ / 2), dim3(64), 0, stream,
                     tiT, W1, idx1T);
  hipLaunchKernelGGL(k_layer2, dim3(F2_), dim3(64), 0, stream,
                     idx1T, W2, out);
}

// Round 2
// 160.994 us; speedup vs baseline: 8.8528x; 8.8528x over previous
//
#include <hip/hip_runtime.h>
#include <stdint.h>

namespace {

constexpr int   B_    = 64;
constexpr int   F0_   = 1876;
constexpr int   F1_   = 1024;
constexpr int   F2_   = 10;
constexpr int   NT_   = 151;
constexpr float DT_   = 0.02f;
constexpr int   NPAD_ = 1880;            // 1876 real + 4 dummy (bin 80), multiple of 8
constexpr int   ROWB_ = F1_ * 4;         // W1T row stride in bytes = 4096

// workspace layout (bytes)
constexpr size_t OFF_W1T  = 0;                          // (1877)*1024*4 = 7,688,192 (extra zero row)
constexpr size_t OFF_PAIR = 7688192;                    // 64*1876*8    =   960,512
constexpr size_t OFF_IDX1 = OFF_PAIR + 960512;          // 64*1024 u8   =    65,536

// ---------------------------------------------------------------------------
// W1[j][i] (1024 x 1876) -> W1T[i][j] (1877 x 1024), row 1876 = zeros (dummy)
// ---------------------------------------------------------------------------
__global__ __launch_bounds__(256) void k_w1t(const float* __restrict__ W1,
                                             float* __restrict__ W1T) {
  __shared__ float tile[64][65];
  const int i0 = blockIdx.x * 64;   // 30 i-tiles (covers 0..1919)
  const int j0 = blockIdx.y * 64;   // 16 j-tiles
  const int t  = threadIdx.x;
  const int c  = t & 63, r4 = t >> 6;
  for (int jj = r4; jj < 64; jj += 4) {
    int i = i0 + c;
    float v = (i < F0_) ? W1[(size_t)(j0 + jj) * F0_ + i] : 0.0f;
    tile[c][jj] = v;
  }
  __syncthreads();
  for (int ii = r4; ii < 64; ii += 4) {
    int i = i0 + ii;
    if (i <= F0_) W1T[(size_t)i * F1_ + j0 + c] = tile[ii][c];
  }
}

// ---------------------------------------------------------------------------
// Deterministic stable counting sort of ti by bin k = ceil(ti*50), per batch.
// One block per b, 64 threads, chunk-local histograms (no atomics).
// Emits sPair[b][pos] = { byte_offset_of_W1T_row(i), ti_bits }.
// ---------------------------------------------------------------------------
__global__ __launch_bounds__(64) void k_sort1(const float* __restrict__ ti,
                                              uint2* __restrict__ sPair) {
  __shared__ uint32_t hist[64][51];
  __shared__ uint32_t bstart[52];
  const int b = blockIdx.x, t = threadIdx.x;
  for (int s = t; s < 64 * 51; s += 64) (&hist[0][0])[s] = 0;
  __syncthreads();

  const float* tib = ti + (size_t)b * F0_;
  const int n0 = t * 30, n1 = (n0 + 30 < F0_) ? n0 + 30 : F0_;
  for (int n = n0; n < n1; ++n) {
    int k = (int)ceilf(tib[n] * 50.0f);
    k = k < 0 ? 0 : (k > 50 ? 50 : k);
    hist[t][k]++;
  }
  __syncthreads();

  if (t < 51) {                       // column-wise exclusive prefix over chunks
    uint32_t run = 0;
    for (int c = 0; c < 64; ++c) { uint32_t x = hist[c][t]; hist[c][t] = run; run += x; }
    bstart[t + 1] = run;              // bin totals
  }
  __syncthreads();
  if (t == 0) {                       // bin-start prefix
    bstart[0] = 0;
    uint32_t acc = 0;
    for (int k2 = 0; k2 < 51; ++k2) { uint32_t c = bstart[k2 + 1]; bstart[k2 + 1] = acc + c; acc += c; }
  }
  __syncthreads();

  uint2* out = sPair + (size_t)b * F0_;
  for (int n = n0; n < n1; ++n) {
    float v = tib[n];
    int k = (int)ceilf(v * 50.0f);
    k = k < 0 ? 0 : (k > 50 ? 50 : k);
    uint32_t pos = bstart[k] + hist[t][k]++;
    out[pos] = make_uint2((uint32_t)n * (uint32_t)ROWB_, __float_as_uint(v));
  }
}

// ---------------------------------------------------------------------------
// Layer-1 main: one wave per (b, jp); lane = j; each wave owns j = jp*128+lane
// and jp*128+64+lane. Walks the sorted stream with register prefix sums,
// crossing checks at bin boundaries (scalar branch), depth-2 load pipeline.
// Grid ordered b-minor so same-jp blocks cluster -> W1T columns L2-resident.
// ---------------------------------------------------------------------------
__global__ __launch_bounds__(64) void k_main1(const uint2* __restrict__ sPair,
                                              const float* __restrict__ W1T,
                                              uint8_t* __restrict__ idx1) {
  __shared__ uint2 pairs[NPAD_];
  const int blk  = blockIdx.x;       // 512
  const int jp   = blk >> 6;         // 0..7
  const int b    = blk & 63;
  const int lane = threadIdx.x;

  const uint2* sp = sPair + (size_t)b * F0_;
  for (int s = lane; s < F0_; s += 64) pairs[s] = sp[s];
  if (lane < NPAD_ - F0_)            // dummy elems: zero W row, bin 80
    pairs[F0_ + lane] = make_uint2((uint32_t)F0_ * (uint32_t)ROWB_, __float_as_uint(1.6f));
  __syncthreads();

  const char* wb   = (const char*)W1T;
  const int   col0 = (jp * 128 + lane) * 4;

  float SA0 = 0.f, SC0 = 0.f, SA1 = 0.f, SC1 = 0.f;
  int id0 = NT_ - 1, id1 = NT_ - 1;
  int kcur = 0;

  uint2 prA[8], prB[8];
  float wA0[8], wA1[8], wB0[8], wB1[8];

  auto loadp = [&](uint2* pr, int base) {
#pragma unroll
    for (int e = 0; e < 8; ++e) pr[e] = pairs[base + e];
  };
  auto loadw = [&](const uint2* pr, float* w0, float* w1) {
#pragma unroll
    for (int e = 0; e < 8; ++e) {
      const char* p = wb + pr[e].x + col0;
      w0[e] = *(const float*)p;
      w1[e] = *(const float*)(p + 256);
    }
  };
  auto proc = [&](const uint2* pr, const float* w0, const float* w1) {
#pragma unroll
    for (int e = 0; e < 8; ++e) {
      float tiv = __uint_as_float(pr[e].y);
      int k = __builtin_amdgcn_readfirstlane((int)ceilf(tiv * 50.0f));
      if (k != kcur) {                 // uniform, rare (<= 81 times total)
        for (int tt = kcur; tt < k; ++tt) {
          float td = (float)tt * DT_;
          float m0 = td * SA0 - SC0;
          float m1 = td * SA1 - SC1;
          if (id0 == NT_ - 1 && m0 >= 1.0f) id0 = tt;
          if (id1 == NT_ - 1 && m1 >= 1.0f) id1 = tt;
        }
        kcur = k;
      }
      SA0 += w0[e]; SC0 = fmaf(w0[e], tiv, SC0);
      SA1 += w1[e]; SC1 = fmaf(w1[e], tiv, SC1);
    }
  };

  loadp(prA, 0); loadw(prA, wA0, wA1);
  loadp(prB, 8); loadw(prB, wB0, wB1);
  int n0 = 0;
  for (; n0 + 32 <= NPAD_; n0 += 16) {
    proc(prA, wA0, wA1);
    loadp(prA, n0 + 16); loadw(prA, wA0, wA1);
    proc(prB, wB0, wB1);
    loadp(prB, n0 + 24); loadw(prB, wB0, wB1);
  }
  // invariant: prA = [n0, n0+8), prB = [n0+8, n0+16)
  proc(prA, wA0, wA1);
  proc(prB, wB0, wB1);
  for (int m = n0 + 16; m < NPAD_; m += 8) {  // at most one group
    loadp(prA, m); loadw(prA, wA0, wA1);
    proc(prA, wA0, wA1);
  }
  // tail timesteps (SA,SC final; dummy weights contributed exactly 0)
  for (int tt = kcur; tt < NT_; ++tt) {
    float td = (float)tt * DT_;
    float m0 = td * SA0 - SC0;
    float m1 = td * SA1 - SC1;
    if (id0 == NT_ - 1 && m0 >= 1.0f) id0 = tt;
    if (id1 == NT_ - 1 && m1 >= 1.0f) id1 = tt;
  }

  uint8_t* ob = idx1 + (size_t)b * F1_ + jp * 128 + lane;
  ob[0]  = (uint8_t)id0;
  ob[64] = (uint8_t)id1;
}

// ---------------------------------------------------------------------------
// Layer-2: brute force. Block = (b,j), 4 waves split the i-range; lane = t.
// 3 accumulators per lane cover t = lane, lane+64, lane+128. Ballot -> first
// crossing; forced spike at t = 150.
// ---------------------------------------------------------------------------
__global__ __launch_bounds__(256) void k_main2(const uint8_t* __restrict__ idx1,
                                               const float* __restrict__ W2,
                                               float* __restrict__ out) {
  __shared__ float wrow[F1_];
  __shared__ float tirow[F1_];
  __shared__ float part[4][3][64];
  const int blk = blockIdx.x;          // 640
  const int b   = blk / 10;
  const int j   = blk - b * 10;
  const int tid = threadIdx.x;
  const int lane = tid & 63, wv = tid >> 6;

  const float*   w = W2  + (size_t)j * F1_;
  const uint8_t* h = idx1 + (size_t)b * F1_;
  for (int s = tid; s < F1_; s += 256) {
    wrow[s]  = w[s];
    tirow[s] = (float)h[s] * DT_;
  }
  __syncthreads();

  const float tl0 = (float)lane * DT_;
  const float tl1 = (float)(lane + 64) * DT_;
  const float tl2 = (float)(lane + 128) * DT_;
  float m0 = 0.f, m1 = 0.f, m2 = 0.f;
  const int i0 = wv * 256;
#pragma unroll 4
  for (int i = i0; i < i0 + 256; ++i) {
    float tiv = tirow[i], ww = wrow[i];
    m0 = fmaf(ww, fmaxf(tl0 - tiv, 0.f), m0);
    m1 = fmaf(ww, fmaxf(tl1 - tiv, 0.f), m1);
    m2 = fmaf(ww, fmaxf(tl2 - tiv, 0.f), m2);
  }
  part[wv][0][lane] = m0;
  part[wv][1][lane] = m1;
  part[wv][2][lane] = m2;
  __syncthreads();

  if (wv == 0) {
    m0 = part[0][0][lane] + part[1][0][lane] + part[2][0][lane] + part[3][0][lane];
    m1 = part[0][1][lane] + part[1][1][lane] + part[2][1][lane] + part[3][1][lane];
    m2 = part[0][2][lane] + part[1][2][lane] + part[2][2][lane] + part[3][2][lane];
    unsigned long long b0 = __ballot(m0 >= 1.0f);
    unsigned long long b1 = __ballot(m1 >= 1.0f);
    unsigned long long b2 = __ballot(m2 >= 1.0f);
    b2 &= (1ull << 23) - 1;            // t <= 150
    b2 |= (1ull << 22);                // forced spike at t = 150
    int tres;
    if (b0)      tres = __ffsll((long long)b0) - 1;
    else if (b1) tres = 64 + __ffsll((long long)b1) - 1;
    else         tres = 128 + __ffsll((long long)b2) - 1;
    if (lane == 0) out[(size_t)b * F2_ + j] = (float)tres * DT_;
  }
}

}  // namespace

// ---------------------------------------------------------------------------
extern "C" void kernel_launch(void* const* d_in, const int* in_sizes, int n_in,
                              void* d_out, int out_size, void* d_ws, size_t ws_size,
                              hipStream_t stream) {
  const float* ti = (const float*)d_in[0];   // [64][1876]
  const float* W1 = (const float*)d_in[1];   // [1024][1876]
  const float* W2 = (const float*)d_in[2];   // [10][1024]
  float* out = (float*)d_out;                // [64][10]

  char* ws = (char*)d_ws;
  float*   W1T   = (float*)(ws + OFF_W1T);
  uint2*   sPair = (uint2*)(ws + OFF_PAIR);
  uint8_t* idx1  = (uint8_t*)(ws + OFF_IDX1);

  hipLaunchKernelGGL(k_w1t,  dim3(30, 16), dim3(256), 0, stream, W1, W1T);
  hipLaunchKernelGGL(k_sort1, dim3(64),    dim3(64),  0, stream, ti, sPair);
  hipLaunchKernelGGL(k_main1, dim3(512),   dim3(64),  0, stream, sPair, W1T, idx1);
  hipLaunchKernelGGL(k_main2, dim3(640),   dim3(256), 0, stream, idx1, W2, out);
}

// Round 3
// 128.123 us; speedup vs baseline: 11.1240x; 1.2566x over previous
//
#include <hip/hip_runtime.h>
#include <stdint.h>

namespace {

constexpr int   B_    = 64;
constexpr int   F0_   = 1876;
constexpr int   F1_   = 1024;
constexpr int   F2_   = 10;
constexpr int   NT_   = 151;
constexpr float DT_   = 0.02f;
constexpr int   NSTR_ = 2048;            // per-b padded stream length (32 blocks of 64)
constexpr int   NBLK_ = 30;              // 64-element blocks actually processed (1920 >= 1876)

// workspace layout (bytes)
constexpr size_t OFF_W1T  = 0;                          // 1877*1024*4 = 7,688,192 (extra zero row)
constexpr size_t OFF_PAIR = 7688192;                    // 64*2048*8   = 1,048,576
constexpr size_t OFF_IDX1 = OFF_PAIR + 1048576;         // 64*1024 u8  =    65,536

// ---------------------------------------------------------------------------
// W1[j][i] (1024 x 1876) -> W1T[i][j] (1877 x 1024), row 1876 = zeros (dummy)
// ---------------------------------------------------------------------------
__global__ __launch_bounds__(256) void k_w1t(const float* __restrict__ W1,
                                             float* __restrict__ W1T) {
  __shared__ float tile[64][65];
  const int i0 = blockIdx.x * 64;   // 30 i-tiles (covers 0..1919)
  const int j0 = blockIdx.y * 64;   // 16 j-tiles
  const int t  = threadIdx.x;
  const int c  = t & 63, r4 = t >> 6;
  for (int jj = r4; jj < 64; jj += 4) {
    int i = i0 + c;
    float v = (i < F0_) ? W1[(size_t)(j0 + jj) * F0_ + i] : 0.0f;
    tile[c][jj] = v;
  }
  __syncthreads();
  for (int ii = r4; ii < 64; ii += 4) {
    int i = i0 + ii;
    if (i <= F0_) W1T[(size_t)i * F1_ + j0 + c] = tile[ii][c];
  }
}

// ---------------------------------------------------------------------------
// Deterministic stable counting sort of ti by bin k = ceil(ti*50), per batch.
// One block per b, 64 threads, chunk-local histograms (no atomics).
// Emits sPair[b][pos] = { (i << 12) | k , ti_bits }, padded to NSTR_ with
// dummy elements (row F0_ = zero weights, bin 80).
// ---------------------------------------------------------------------------
__global__ __launch_bounds__(64) void k_sort1(const float* __restrict__ ti,
                                              uint2* __restrict__ sPair) {
  __shared__ uint32_t hist[64][51];
  __shared__ uint32_t bstart[52];
  const int b = blockIdx.x, t = threadIdx.x;
  for (int s = t; s < 64 * 51; s += 64) (&hist[0][0])[s] = 0;
  __syncthreads();

  const float* tib = ti + (size_t)b * F0_;
  const int n0 = t * 30, n1 = (n0 + 30 < F0_) ? n0 + 30 : F0_;
  for (int n = n0; n < n1; ++n) {
    int k = (int)ceilf(tib[n] * 50.0f);
    k = k < 0 ? 0 : (k > 50 ? 50 : k);
    hist[t][k]++;
  }
  __syncthreads();

  if (t < 51) {                       // column-wise exclusive prefix over chunks
    uint32_t run = 0;
    for (int c = 0; c < 64; ++c) { uint32_t x = hist[c][t]; hist[c][t] = run; run += x; }
    bstart[t + 1] = run;              // bin totals
  }
  __syncthreads();
  if (t == 0) {                       // bin-start prefix
    bstart[0] = 0;
    uint32_t acc = 0;
    for (int k2 = 0; k2 < 51; ++k2) { uint32_t c = bstart[k2 + 1]; bstart[k2 + 1] = acc + c; acc += c; }
  }
  __syncthreads();

  uint2* out = sPair + (size_t)b * NSTR_;
  for (int n = n0; n < n1; ++n) {
    float v = tib[n];
    int k = (int)ceilf(v * 50.0f);
    k = k < 0 ? 0 : (k > 50 ? 50 : k);
    uint32_t pos = bstart[k] + hist[t][k]++;
    out[pos] = make_uint2(((uint32_t)n << 12) | (uint32_t)k, __float_as_uint(v));
  }
  // dummy padding: zero-weight row F0_, bin 80 (> any real bin)
  for (int s = t; s < NSTR_ - F0_; s += 64)
    out[F0_ + s] = make_uint2(((uint32_t)F0_ << 12) | 80u, __float_as_uint(1.6f));
}

// ---------------------------------------------------------------------------
// Layer-1 main: 1024 blocks = (b major, jp minor), one wave each, lane = j
// (j = jp*64 + lane). Pairs read coalesced per-lane (1 dwordx2 / 64 elems),
// broadcast via v_readlane at use; bin boundaries via one ballot per block +
// scalar bit tests. Weights pipelined depth-3 in groups of 16.
// b-major grid => per-XCD W1T working set = 2 column slices (~1 MB) -> L2-fit.
// ---------------------------------------------------------------------------
__global__ __launch_bounds__(64) void k_main1(const uint2* __restrict__ sPair,
                                              const float* __restrict__ W1T,
                                              uint8_t* __restrict__ idx1) {
  const int blk  = blockIdx.x;        // 1024
  const int b    = blk >> 4;
  const int jp   = blk & 15;
  const int lane = threadIdx.x;

  const uint2* sp = sPair + (size_t)b * NSTR_;
  const char*  wtb = (const char*)W1T;
  const uint32_t col4 = (uint32_t)((jp << 6) + lane) * 4u;   // byte offset of column j

  float SA = 0.f, SC = 0.f;
  int   id = NT_ - 1;
  int   kcur = 0;
  uint32_t kprev = 0;

  uint2 pvA, pvB, pvN;
  uint32_t klaneA = 0;
  unsigned long long bmaskA = 0;

  float w0a[16], w1a[16], w2a[16];

#define LDW(warr, pv, q)                                                      \
  _Pragma("unroll") for (int e = 0; e < 16; ++e) {                            \
    uint32_t ro = (uint32_t)__builtin_amdgcn_readlane((pv).x, (q) + e) &      \
                  0xFFFFF000u;                                                \
    (warr)[e] = *(const float*)(wtb + ro + col4);                             \
  }

#define BLKMASK()                                                             \
  {                                                                           \
    klaneA = pvA.x & 4095u;                                                   \
    uint32_t kup = (uint32_t)__shfl_up((int)klaneA, 1);                       \
    unsigned long long bm = __ballot(klaneA != kup);                          \
    uint32_t k0 = (uint32_t)__builtin_amdgcn_readlane(klaneA, 0);             \
    bm = (bm & ~1ull) | ((k0 != kprev) ? 1ull : 0ull);                        \
    bmaskA = bm;                                                              \
    kprev = (uint32_t)__builtin_amdgcn_readlane(klaneA, 63);                  \
  }

#define PROCG(warr, q)                                                        \
  _Pragma("unroll") for (int e = 0; e < 16; ++e) {                            \
    if ((bmaskA >> ((q) + e)) & 1ull) {                                       \
      int kb = (int)__builtin_amdgcn_readlane(klaneA, (q) + e);               \
      for (int tt = kcur; tt < kb; ++tt) {                                    \
        float m = (float)tt * DT_ * SA - SC;                                  \
        if (id == NT_ - 1 && m >= 1.0f) id = tt;                              \
      }                                                                       \
      kcur = kb;                                                              \
    }                                                                         \
    float tiv = __uint_as_float(                                              \
        (uint32_t)__builtin_amdgcn_readlane(pvA.y, (q) + e));                 \
    SA += (warr)[e];                                                          \
    SC = fmaf((warr)[e], tiv, SC);                                            \
  }

#define BODY(wa, wb, wc, n)                                                   \
  BLKMASK();                                                                  \
  LDW(wc, pvA, 32);                                                           \
  PROCG(wa, 0);                                                               \
  LDW(wa, pvA, 48);                                                           \
  PROCG(wb, 16);                                                              \
  pvN = sp[((n) + 2) * 64 + lane];                                            \
  LDW(wb, pvB, 0);                                                            \
  PROCG(wc, 32);                                                              \
  LDW(wc, pvB, 16);                                                           \
  PROCG(wa, 48);                                                              \
  pvA = pvB;                                                                  \
  pvB = pvN;

  // prologue
  pvA = sp[lane];
  pvB = sp[64 + lane];
  LDW(w0a, pvA, 0);
  LDW(w1a, pvA, 16);

#pragma unroll 1
  for (int n = 0; n < NBLK_; n += 3) {
    BODY(w0a, w1a, w2a, n);
    BODY(w1a, w2a, w0a, n + 1);
    BODY(w2a, w0a, w1a, n + 2);
  }

#undef BODY
#undef PROCG
#undef BLKMASK
#undef LDW

  // tail timesteps (dummy elements contributed exactly 0 weight)
  for (int tt = kcur; tt < NT_; ++tt) {
    float m = (float)tt * DT_ * SA - SC;
    if (id == NT_ - 1 && m >= 1.0f) id = tt;
  }

  idx1[((size_t)b << 10) + (jp << 6) + lane] = (uint8_t)id;
}

// ---------------------------------------------------------------------------
// Layer-2: brute force. Block = (b,j), 4 waves split the i-range; lane = t.
// ---------------------------------------------------------------------------
__global__ __launch_bounds__(256) void k_main2(const uint8_t* __restrict__ idx1,
                                               const float* __restrict__ W2,
                                               float* __restrict__ out) {
  __shared__ float wrow[F1_];
  __shared__ float tirow[F1_];
  __shared__ float part[4][3][64];
  const int blk = blockIdx.x;          // 640
  const int b   = blk / 10;
  const int j   = blk - b * 10;
  const int tid = threadIdx.x;
  const int lane = tid & 63, wv = tid >> 6;

  const float*   w = W2  + (size_t)j * F1_;
  const uint8_t* h = idx1 + (size_t)b * F1_;
  for (int s = tid; s < F1_; s += 256) {
    wrow[s]  = w[s];
    tirow[s] = (float)h[s] * DT_;
  }
  __syncthreads();

  const float tl0 = (float)lane * DT_;
  const float tl1 = (float)(lane + 64) * DT_;
  const float tl2 = (float)(lane + 128) * DT_;
  float m0 = 0.f, m1 = 0.f, m2 = 0.f;
  const int i0 = wv * 256;
#pragma unroll 4
  for (int i = i0; i < i0 + 256; ++i) {
    float tiv = tirow[i], ww = wrow[i];
    m0 = fmaf(ww, fmaxf(tl0 - tiv, 0.f), m0);
    m1 = fmaf(ww, fmaxf(tl1 - tiv, 0.f), m1);
    m2 = fmaf(ww, fmaxf(tl2 - tiv, 0.f), m2);
  }
  part[wv][0][lane] = m0;
  part[wv][1][lane] = m1;
  part[wv][2][lane] = m2;
  __syncthreads();

  if (wv == 0) {
    m0 = part[0][0][lane] + part[1][0][lane] + part[2][0][lane] + part[3][0][lane];
    m1 = part[0][1][lane] + part[1][1][lane] + part[2][1][lane] + part[3][1][lane];
    m2 = part[0][2][lane] + part[1][2][lane] + part[2][2][lane] + part[3][2][lane];
    unsigned long long b0 = __ballot(m0 >= 1.0f);
    unsigned long long b1 = __ballot(m1 >= 1.0f);
    unsigned long long b2 = __ballot(m2 >= 1.0f);
    b2 &= (1ull << 23) - 1;            // t <= 150
    b2 |= (1ull << 22);                // forced spike at t = 150
    int tres;
    if (b0)      tres = __ffsll((long long)b0) - 1;
    else if (b1) tres = 64 + __ffsll((long long)b1) - 1;
    else         tres = 128 + __ffsll((long long)b2) - 1;
    if (lane == 0) out[(size_t)b * F2_ + j] = (float)tres * DT_;
  }
}

}  // namespace

// ---------------------------------------------------------------------------
extern "C" void kernel_launch(void* const* d_in, const int* in_sizes, int n_in,
                              void* d_out, int out_size, void* d_ws, size_t ws_size,
                              hipStream_t stream) {
  const float* ti = (const float*)d_in[0];   // [64][1876]
  const float* W1 = (const float*)d_in[1];   // [1024][1876]
  const float* W2 = (const float*)d_in[2];   // [10][1024]
  float* out = (float*)d_out;                // [64][10]

  char* ws = (char*)d_ws;
  float*   W1T   = (float*)(ws + OFF_W1T);
  uint2*   sPair = (uint2*)(ws + OFF_PAIR);
  uint8_t* idx1  = (uint8_t*)(ws + OFF_IDX1);

  hipLaunchKernelGGL(k_w1t,   dim3(30, 16), dim3(256), 0, stream, W1, W1T);
  hipLaunchKernelGGL(k_sort1, dim3(64),     dim3(64),  0, stream, ti, sPair);
  hipLaunchKernelGGL(k_main1, dim3(1024),   dim3(64),  0, stream, sPair, W1T, idx1);
  hipLaunchKernelGGL(k_main2, dim3(640),    dim3(256), 0, stream, idx1, W2, out);
}

// Round 5
// 77.378 us; speedup vs baseline: 18.4192x; 1.6558x over previous
//
#include <hip/hip_runtime.h>
#include <stdint.h>

namespace {

constexpr int   B_    = 64;
constexpr int   F0_   = 1876;
constexpr int   F1_   = 1024;
constexpr int   F2_   = 10;
constexpr int   NT_   = 151;
constexpr float DT_   = 0.02f;
constexpr int   NSTR_ = 1920;     // padded stream (4 chunks of 480)
constexpr int   CHUNK_= 480;
constexpr int   NGRP_ = 60;       // groups of 8 per chunk
constexpr int   NB1_  = 51;       // real bins 0..50
constexpr float SCL_  = 67108864.0f;       // 2^26 fixed-point scale
constexpr float ISCL_ = 1.0f / 67108864.0f;

// workspace layout (bytes)
constexpr size_t OFF_W1T  = 0;                           // 1920*1024*4 = 7,864,320
constexpr size_t OFF_PAIR = 7864320;                     // 64*1920*8   =   983,040
constexpr size_t OFF_IDX1 = OFF_PAIR + 983040;           // 64*1024 u8  =    65,536

// ---------------------------------------------------------------------------
// W1[j][i] (1024x1876 f32) -> W1T[i][j] (1920x1024 f32), rows >=1876 zero.
// ---------------------------------------------------------------------------
__global__ __launch_bounds__(256) void k_w1t(const float* __restrict__ W1,
                                             float* __restrict__ W1T) {
  __shared__ float tile[64][65];
  const int i0 = blockIdx.x * 64;   // 30 tiles -> rows 0..1919
  const int j0 = blockIdx.y * 64;   // 16 tiles
  const int t  = threadIdx.x;
  const int c  = t & 63, r4 = t >> 6;
  for (int jj = r4; jj < 64; jj += 4) {
    int i = i0 + c;
    float v = (i < F0_) ? W1[(size_t)(j0 + jj) * F0_ + i] : 0.0f;
    tile[c][jj] = v;
  }
  __syncthreads();
  for (int ii = r4; ii < 64; ii += 4) {
    int i = i0 + ii;
    W1T[(size_t)i * F1_ + j0 + c] = tile[ii][c];
  }
}

// ---------------------------------------------------------------------------
// Deterministic stable counting sort of ti by bin k = ceil(ti*50), per batch.
// 64 blocks x 256 threads. Emits sPair[b][pos] = { (i<<12)|k , ti_bits },
// padded to NSTR_ with dummies (row 1876 = zero weights, bin 80).
// ---------------------------------------------------------------------------
__global__ __launch_bounds__(256) void k_sort1(const float* __restrict__ ti,
                                               uint2* __restrict__ sPair) {
  __shared__ uint32_t hist[256][NB1_];
  __shared__ uint32_t bstart[NB1_ + 1];
  const int b = blockIdx.x, t = threadIdx.x;
  for (int k = 0; k < NB1_; ++k) hist[t][k] = 0;
  __syncthreads();

  const float* tib = ti + (size_t)b * F0_;
  const int n0 = t * 8;
  const int n1 = (n0 + 8 < F0_) ? n0 + 8 : F0_;
  for (int n = n0; n < n1; ++n) {
    int k = (int)ceilf(tib[n] * 50.0f);
    k = k < 0 ? 0 : (k > 50 ? 50 : k);
    hist[t][k]++;
  }
  __syncthreads();

  if (t < NB1_) {                    // column-wise exclusive prefix over chunks
    uint32_t run = 0;
    for (int c = 0; c < 256; ++c) { uint32_t x = hist[c][t]; hist[c][t] = run; run += x; }
    bstart[t + 1] = run;
  }
  __syncthreads();
  if (t == 0) {
    bstart[0] = 0;
    uint32_t acc = 0;
    for (int k = 0; k < NB1_; ++k) { uint32_t c = bstart[k + 1]; bstart[k + 1] = acc + c; acc += c; }
  }
  __syncthreads();

  uint2* out = sPair + (size_t)b * NSTR_;
  for (int n = n0; n < n1; ++n) {
    float v = tib[n];
    int k = (int)ceilf(v * 50.0f);
    k = k < 0 ? 0 : (k > 50 ? 50 : k);
    uint32_t pos = bstart[k] + hist[t][k]++;
    out[pos] = make_uint2(((uint32_t)n << 12) | (uint32_t)k, __float_as_uint(v));
  }
  for (int s = t; s < NSTR_ - F0_; s += 256)
    out[F0_ + s] = make_uint2(((uint32_t)F0_ << 12) | 80u, __float_as_uint(1.6f));
}

// ---------------------------------------------------------------------------
// Layer-1 main: 1024 blocks = (b major, jp minor), 4 waves each.
// Wave wv walks sorted-stream chunk [wv*480, wv*480+480): scalar (uniform)
// pair stream + per-lane f32 weight loads (saddr + v_col), register (SA,SC);
// per-bin deltas dumped at (uniform, rare) bin boundaries into LDS as
// FIXED-POINT int32 atomics (order-independent -> bit-deterministic).
// Phase 2: prefix over bins, each wave checks its t-range, min-reduce.
// ---------------------------------------------------------------------------
__global__ __launch_bounds__(256) void k_main1(const uint2* __restrict__ sPair,
                                               const float* __restrict__ W1T,
                                               uint8_t* __restrict__ idx1) {
  __shared__ int  binAi[NB1_][64];
  __shared__ int  binCi[NB1_][64];
  __shared__ int  cand[4][64];
  const int blk  = blockIdx.x;      // 1024
  const int b    = blk >> 4;
  const int jp   = blk & 15;
  const int tid  = threadIdx.x;
  const int lane = tid & 63;
  const int wv   = __builtin_amdgcn_readfirstlane(tid >> 6);  // force SGPR

  for (int s = tid; s < NB1_ * 64; s += 256) {
    (&binAi[0][0])[s] = 0;
    (&binCi[0][0])[s] = 0;
  }
  __syncthreads();

  const uint2* __restrict__ spw = sPair + (size_t)b * NSTR_ + wv * CHUNK_;
  const char*  __restrict__ wb  = (const char*)W1T;
  const uint32_t col4 = (uint32_t)(jp * 64 + lane) * 4u;  // byte offset in row

  float SA = 0.f, SC = 0.f, SAp = 0.f, SCp = 0.f;
  uint32_t kcur;

  uint2 Pb[3][8];   // wave-uniform pair stream
  float W[3][8];    // per-lane weights

#define RDP(buf, g) {                                                         \
  _Pragma("unroll") for (int e = 0; e < 8; ++e) Pb[buf][e] = spw[(g) * 8 + e]; }

#define ISSW(buf) {                                                           \
  _Pragma("unroll") for (int e = 0; e < 8; ++e) {                             \
    W[buf][e] = *(const float*)(wb + (Pb[buf][e].x & ~4095u) + col4); } }

#define DUMP() { if (kcur < (uint32_t)NB1_) {                                 \
    atomicAdd(&binAi[kcur][lane], __float2int_rn((SA - SAp) * SCL_));         \
    atomicAdd(&binCi[kcur][lane], __float2int_rn((SC - SCp) * SCL_)); }       \
  SAp = SA; SCp = SC; }

#define PROC(buf) {                                                           \
  uint32_t kend = Pb[buf][7].x & 4095u;                                       \
  if (kend == kcur) {  /* fast path: no boundary inside group */              \
    _Pragma("unroll") for (int e = 0; e < 8; ++e) {                           \
      float w = W[buf][e];                                                    \
      SA += w; SC = fmaf(w, __uint_as_float(Pb[buf][e].y), SC); }             \
  } else {                                                                    \
    _Pragma("unroll") for (int e = 0; e < 8; ++e) {                           \
      uint32_t kb = Pb[buf][e].x & 4095u;                                     \
      if (kb != kcur) { DUMP(); kcur = kb; }                                  \
      float w = W[buf][e];                                                    \
      SA += w; SC = fmaf(w, __uint_as_float(Pb[buf][e].y), SC); }             \
  } }

  // prologue: pairs 3 groups deep, weights 2 groups deep
  RDP(0, 0); RDP(1, 1);
  ISSW(0);
  RDP(2, 2);
  ISSW(1);
  kcur = Pb[0][0].x & 4095u;

  // steady state: at loop top Pb0=g(k), Pb1=g(k+1), Pb2=g(k+2),
  // weights issued for g(k), g(k+1). Processes g(k..k+2).
#pragma unroll 1
  for (int k = 0; k < NGRP_ - 3; k += 3) {   // k = 0,3,...,54
    ISSW(2); PROC(0); RDP(0, k + 3);
    ISSW(0); PROC(1); RDP(1, k + 4);
    ISSW(1); PROC(2); RDP(2, k + 5);
  }
  // epilogue: Pb0=g57, Pb1=g58, Pb2=g59; weights issued through g58
  ISSW(2);
  PROC(0);
  PROC(1);
  PROC(2);
  DUMP();        // final real bin (skipped if kcur is dummy bin 80)

#undef PROC
#undef DUMP
#undef ISSW
#undef RDP

  __syncthreads();

  // phase 2: prefix over bins; wave wv checks t in [wv*38, t1)
  {
    float SA2 = 0.f, SC2 = 0.f;
    int cnd = 151;
    const int t0 = wv * 38;
    const int t1 = (wv == 3) ? NT_ : t0 + 38;
    for (int t = 0; t < t1; ++t) {
      if (t < NB1_) {
        SA2 += (float)binAi[t][lane] * ISCL_;
        SC2 += (float)binCi[t][lane] * ISCL_;
      }
      if (t >= t0 && cnd == 151) {
        float m = (float)t * DT_ * SA2 - SC2;
        if (m >= 1.0f) cnd = t;
      }
    }
    cand[wv][lane] = cnd;
  }
  __syncthreads();
  if (tid < 64) {
    int id = min(min(cand[0][lane], cand[1][lane]),
                 min(cand[2][lane], cand[3][lane]));
    id = min(id, NT_ - 1);               // forced spike at last timestep
    idx1[((size_t)b << 10) + (jp << 6) + lane] = (uint8_t)id;
  }
}

// ---------------------------------------------------------------------------
// Layer-2: brute force. Block = (b,j), 4 waves split the i-range; lane = t.
// ---------------------------------------------------------------------------
__global__ __launch_bounds__(256) void k_main2(const uint8_t* __restrict__ idx1,
                                               const float* __restrict__ W2,
                                               float* __restrict__ out) {
  __shared__ float wrow[F1_];
  __shared__ float tirow[F1_];
  __shared__ float part[4][3][64];
  const int blk = blockIdx.x;          // 640
  const int b   = blk / 10;
  const int j   = blk - b * 10;
  const int tid = threadIdx.x;
  const int lane = tid & 63, wvv = tid >> 6;

  const float*   w = W2  + (size_t)j * F1_;
  const uint8_t* h = idx1 + (size_t)b * F1_;
  for (int s = tid; s < F1_; s += 256) {
    wrow[s]  = w[s];
    tirow[s] = (float)h[s] * DT_;
  }
  __syncthreads();

  const float tl0 = (float)lane * DT_;
  const float tl1 = (float)(lane + 64) * DT_;
  const float tl2 = (float)(lane + 128) * DT_;
  float m0 = 0.f, m1 = 0.f, m2 = 0.f;
  const int i0 = wvv * 256;
#pragma unroll 4
  for (int i = i0; i < i0 + 256; ++i) {
    float tiv = tirow[i], ww = wrow[i];
    m0 = fmaf(ww, fmaxf(tl0 - tiv, 0.f), m0);
    m1 = fmaf(ww, fmaxf(tl1 - tiv, 0.f), m1);
    m2 = fmaf(ww, fmaxf(tl2 - tiv, 0.f), m2);
  }
  part[wvv][0][lane] = m0;
  part[wvv][1][lane] = m1;
  part[wvv][2][lane] = m2;
  __syncthreads();

  if (wvv == 0) {
    m0 = part[0][0][lane] + part[1][0][lane] + part[2][0][lane] + part[3][0][lane];
    m1 = part[0][1][lane] + part[1][1][lane] + part[2][1][lane] + part[3][1][lane];
    m2 = part[0][2][lane] + part[1][2][lane] + part[2][2][lane] + part[3][2][lane];
    unsigned long long b0 = __ballot(m0 >= 1.0f);
    unsigned long long b1 = __ballot(m1 >= 1.0f);
    unsigned long long b2 = __ballot(m2 >= 1.0f);
    b2 &= (1ull << 23) - 1;            // t <= 150
    b2 |= (1ull << 22);                // forced spike at t = 150
    int tres;
    if (b0)      tres = __ffsll((long long)b0) - 1;
    else if (b1) tres = 64 + __ffsll((long long)b1) - 1;
    else         tres = 128 + __ffsll((long long)b2) - 1;
    if (lane == 0) out[(size_t)b * F2_ + j] = (float)tres * DT_;
  }
}

}  // namespace

// ---------------------------------------------------------------------------
extern "C" void kernel_launch(void* const* d_in, const int* in_sizes, int n_in,
                              void* d_out, int out_size, void* d_ws, size_t ws_size,
                              hipStream_t stream) {
  const float* ti = (const float*)d_in[0];   // [64][1876]
  const float* W1 = (const float*)d_in[1];   // [1024][1876]
  const float* W2 = (const float*)d_in[2];   // [10][1024]
  float* out = (float*)d_out;                // [64][10]

  char* ws = (char*)d_ws;
  float*   W1T  = (float*)(ws + OFF_W1T);
  uint2*   sPr  = (uint2*)(ws + OFF_PAIR);
  uint8_t* idx1 = (uint8_t*)(ws + OFF_IDX1);

  hipLaunchKernelGGL(k_w1t,   dim3(30, 16), dim3(256), 0, stream, W1, W1T);
  hipLaunchKernelGGL(k_sort1, dim3(64),     dim3(256), 0, stream, ti, sPr);
  hipLaunchKernelGGL(k_main1, dim3(1024),   dim3(256), 0, stream, sPr, W1T, idx1);
  hipLaunchKernelGGL(k_main2, dim3(640),    dim3(256), 0, stream, idx1, W2, out);
}